// Round 3
// baseline (717.919 us; speedup 1.0000x reference)
//
#include <hip/hip_runtime.h>

// MoE top-2, D=1024, DFF=4096, E=8, T=4096. Sparse grouped-GEMM, bf16 MFMA.
// GEMM: 256x256 tile, BK=64, 8 waves (2M x 4N), per-wave 128x64. Faithful
// 8-phase schedule (m201/m248 template): per K-tile 4 quadrant phases, each
// {ds_read | 2x gld16 | counted vmcnt | barrier | lgkm0 | setprio 16-MFMA |
// barrier}. Conflict-free granule-XOR LDS (verified: 0 conflicts in r2),
// steady-state vmcnt(4) (never drains), XCD strip pinning.

#define T_TOK 4096
#define DMODEL 1024
#define DFF 4096
#define NE 8
#define CAP 10240           // max aligned slots: 8192 + 8*255 -> 10232, padded
#define MT_CAP 32           // max 256-row m-tiles per expert (8192/256)

typedef __bf16 bf16x8 __attribute__((ext_vector_type(8)));
typedef float f32x4 __attribute__((ext_vector_type(4)));

#define VMW(n) asm volatile("s_waitcnt vmcnt(" #n ")" ::: "memory")
#define NOP0 ((void)0)

__device__ __forceinline__ unsigned short f2bf(float f) {
    union { float f; unsigned u; } v; v.f = f;
    unsigned r = v.u + 0x7fffu + ((v.u >> 16) & 1u);
    return (unsigned short)(r >> 16);
}

// async 16B/lane global->LDS. LDS dest = base + lane*16 (wave-uniform base).
__device__ __forceinline__ void gld16(const unsigned short* g, unsigned short* l) {
    __builtin_amdgcn_global_load_lds(
        (const __attribute__((address_space(1))) unsigned int*)g,
        (__attribute__((address_space(3))) unsigned int*)l, 16, 0, 0);
}

// meta layout (ints): [0..7] count, [8..15] cursor, [16..23] aligned, [24..32] off[9], [33] total
__global__ __launch_bounds__(256) void k_router(const float* __restrict__ x,
                                                const float* __restrict__ Wr,
                                                int* __restrict__ meta,
                                                int* __restrict__ tg_idx,
                                                float* __restrict__ tg_gate) {
    int wave = threadIdx.x >> 6, lane = threadIdx.x & 63;
    int t = blockIdx.x * 4 + wave;
    double acc[NE];
#pragma unroll
    for (int e = 0; e < NE; e++) acc[e] = 0.0;
    const float* xr = x + (size_t)t * DMODEL;
#pragma unroll 4
    for (int j = 0; j < 16; j++) {
        int k = j * 64 + lane;
        double xv = (double)xr[k];
        const float4* wr = (const float4*)(Wr + k * NE);
        float4 w0 = wr[0], w1 = wr[1];
        acc[0] += xv * (double)w0.x; acc[1] += xv * (double)w0.y;
        acc[2] += xv * (double)w0.z; acc[3] += xv * (double)w0.w;
        acc[4] += xv * (double)w1.x; acc[5] += xv * (double)w1.y;
        acc[6] += xv * (double)w1.z; acc[7] += xv * (double)w1.w;
    }
#pragma unroll
    for (int off = 32; off; off >>= 1)
#pragma unroll
        for (int e = 0; e < NE; e++) acc[e] += __shfl_xor(acc[e], off);
    if (lane == 0) {
        double v1 = -1e300, v2 = -1e300; int i1 = 0, i2 = 0;
#pragma unroll
        for (int e = 0; e < NE; e++) {
            double v = acc[e];
            if (v > v1) { v2 = v1; i2 = i1; v1 = v; i1 = e; }
            else if (v > v2) { v2 = v; i2 = e; }
        }
        double g1 = 1.0 / (1.0 + exp(v2 - v1));
        tg_idx[t * 2] = i1; tg_idx[t * 2 + 1] = i2;
        tg_gate[t * 2] = (float)g1; tg_gate[t * 2 + 1] = (float)(1.0 - g1);
        atomicAdd(&meta[i1], 1);
        atomicAdd(&meta[i2], 1);
    }
}

__global__ void k_scan(int* __restrict__ meta) {
    if (threadIdx.x == 0) {
        int acc = 0;
        for (int e = 0; e < NE; e++) {
            int a = (meta[e] + 255) & ~255;
            meta[16 + e] = a;
            meta[24 + e] = acc;
            acc += a;
        }
        meta[24 + NE] = acc;
        meta[33] = acc;
    }
}

__global__ __launch_bounds__(256) void k_build(const int* __restrict__ tg_idx,
                                               const float* __restrict__ tg_gate,
                                               int* __restrict__ meta,
                                               int* __restrict__ tos,
                                               float* __restrict__ gos,
                                               int* __restrict__ sot) {
    int t = blockIdx.x * 256 + threadIdx.x;
#pragma unroll
    for (int kk = 0; kk < 2; kk++) {
        int e = tg_idx[t * 2 + kk];
        int pos = atomicAdd(&meta[8 + e], 1);
        int slot = meta[24 + e] + pos;
        tos[slot] = t;
        gos[slot] = tg_gate[t * 2 + kk];
        sot[t * 2 + kk] = slot;
    }
}

__global__ __launch_bounds__(256) void k_gather(const float* __restrict__ x,
                                                const int* __restrict__ tos,
                                                const int* __restrict__ meta,
                                                unsigned short* __restrict__ xg) {
    int s = blockIdx.x;
    if (s >= meta[33]) return;
    int t = tos[s];
    int tid = threadIdx.x;
#pragma unroll
    for (int j = 0; j < 4; j++) {
        int k = tid + j * 256;
        float v = (t >= 0) ? x[(size_t)t * DMODEL + k] : 0.f;
        xg[(size_t)s * DMODEL + k] = f2bf(v);
    }
}

// Both weight transposes in one launch. id<4096: W1 (R=1024,C=4096);
// else W2 (R=4096,C=1024). in [E][R][C] f32 -> out [E][C][R] bf16.
__global__ __launch_bounds__(256) void k_transpose2(const float* __restrict__ W1,
                                                    unsigned short* __restrict__ W1t,
                                                    const float* __restrict__ W2,
                                                    unsigned short* __restrict__ W2t) {
    int id = blockIdx.x;
    const float* in; unsigned short* out; int R, C, rem;
    if (id < 4096) { in = W1; out = W1t; R = DMODEL; C = DFF; rem = id; }
    else           { in = W2; out = W2t; R = DFF; C = DMODEL; rem = id - 4096; }
    int e = rem >> 9, r2 = rem & 511;
    int nbx = C >> 7;
    int bx = r2 % nbx, by = r2 / nbx;
    const float* src = in + (size_t)e * R * C;
    unsigned short* dst = out + (size_t)e * R * C;
    int g = threadIdx.x >> 3, l8 = threadIdx.x & 7;
    int rb = by * 64 + l8 * 8;
    int cb = bx * 128 + g * 4;
    f32x4 v[8];
#pragma unroll
    for (int i = 0; i < 8; i++)
        v[i] = *(const f32x4*)&src[(size_t)(rb + i) * C + cb];
#pragma unroll
    for (int j = 0; j < 4; j++) {
        unsigned short o[8];
#pragma unroll
        for (int i = 0; i < 8; i++) o[i] = f2bf(v[i][j]);
        *(uint4*)&dst[(size_t)(cb + j) * R + rb] = *(uint4*)o;
    }
}

// MODE 1: h = relu(xg @ W1t[e] + b1[e]) -> bf16 H.
// MODE 2: y[kq][slot] = h(kq half) @ W2t[e]  (split-K=2; bias+gate in combine)
template <int MODE>
__global__ __launch_bounds__(512, 2) void k_gemm(const unsigned short* __restrict__ A,
                                                 const unsigned short* __restrict__ Bt,
                                                 const float* __restrict__ bias,
                                                 const int* __restrict__ meta,
                                                 unsigned short* __restrict__ H,
                                                 float* __restrict__ Y) {
    constexpr int KFULL = (MODE == 1) ? DMODEL : DFF;
    constexpr int K     = (MODE == 1) ? DMODEL : DFF / 2;
    constexpr int N     = (MODE == 1) ? DFF : DMODEL;
    constexpr int NT    = K / 64;                     // K-tiles

    int L = blockIdx.x;
    int xcd = L & 7, c = L >> 3;
    int mt = c & 31, sgrp = c >> 5;
    int s = (sgrp << 3) | xcd;
    int e, kq, nt;
    if constexpr (MODE == 1) { e = s >> 4; nt = s & 15; kq = 0; }
    else                     { e = s >> 3; kq = (s >> 2) & 1; nt = s & 3; }
    if (mt * 256 >= meta[16 + e]) return;
    int row0 = meta[24 + e] + mt * 256;
    int col0 = nt * 256;
    const unsigned short* Ae = A + (size_t)row0 * KFULL + kq * K;
    const unsigned short* Be = Bt + (size_t)e * N * KFULL + (size_t)col0 * KFULL + kq * K;
    const float* be = bias + (size_t)e * N;

    // [buf][256 rows][64 k] bf16; rows are 128B. Granule g of row r holds
    // global k-granule g^(r&7) (swizzle on gld16 source; reads conflict-free,
    // verified 0 SQ_LDS_BANK_CONFLICT in round 2). B rows stored j-pair-
    // permuted: LDS rows 0-127 = {wn*64 + 0..31}, rows 128-255 = {wn*64+32..63}
    // so each staged half-tile (64 LDS rows x 2 calls) is phase-aligned.
    __shared__ __align__(16) unsigned short As[2][256 * 64];  // 64 KiB
    __shared__ __align__(16) unsigned short Bs[2][256 * 64];  // 64 KiB

    int tid = threadIdx.x;
    int lane = tid & 63, wv = tid >> 6;      // 8 waves
    int wm = wv >> 2, wn = wv & 3;           // 2M x 4N wave grid, per-wave 128x64
    int q = lane >> 4, r16 = lane & 15;
    int sw = r16 & 7;
    int rl = lane >> 3, gsl = lane & 7;
    int skoff = (gsl ^ rl) << 3;             // pre-swizzled k-short offset

    // one stage call = 64 LDS rows (8 rows/wave), 1 gld16/thread
    auto stageA = [&](int bn, int cc, int tn) {
        gld16(Ae + (size_t)(cc * 64 + wv * 8 + rl) * KFULL + tn * 64 + skoff,
              &As[bn][(cc * 64 + wv * 8) * 64]);
    };
    auto stageB = [&](int bn, int cc, int tn) {
        int r = cc * 64 + wv * 8 + rl;
        int grow = ((r & 127) >> 5) * 64 + (r >> 7) * 32 + (r & 31);  // j-pair perm
        gld16(Be + (size_t)grow * KFULL + tn * 64 + skoff,
              &Bs[bn][(cc * 64 + wv * 8) * 64]);
    };

    f32x4 acc[8][4];
#pragma unroll
    for (int i = 0; i < 8; i++)
#pragma unroll
        for (int j = 0; j < 4; j++) acc[i][j] = (f32x4){0.f, 0.f, 0.f, 0.f};

    bf16x8 aA[4][2], bB[2][2];

#define RD_A(dst, ii, kk) dst = *(const bf16x8*)&Ab[(wm * 128 + (ii) * 16 + r16) * 64 + ((((kk) * 4 + q) ^ sw) << 3)]
#define RD_B(dst, jj, kk) dst = *(const bf16x8*)&Bb[(((jj) >> 1) * 128 + wn * 32 + ((jj) & 1) * 16 + r16) * 64 + ((((kk) * 4 + q) ^ sw) << 3)]

#define MFMA4(ai, bj, ci, cj)                                                                          \
    acc[ci][cj] = __builtin_amdgcn_mfma_f32_16x16x32_bf16(aA[ai][0], bB[bj][0], acc[ci][cj], 0, 0, 0); \
    acc[ci][cj] = __builtin_amdgcn_mfma_f32_16x16x32_bf16(aA[ai][1], bB[bj][1], acc[ci][cj], 0, 0, 0)

#define CLUSTER(i0, j0)                                      \
    __builtin_amdgcn_s_setprio(1);                           \
    MFMA4(0, 0, (i0) + 0, (j0)); MFMA4(0, 1, (i0) + 0, (j0) + 1); \
    MFMA4(1, 0, (i0) + 1, (j0)); MFMA4(1, 1, (i0) + 1, (j0) + 1); \
    MFMA4(2, 0, (i0) + 2, (j0)); MFMA4(2, 1, (i0) + 2, (j0) + 1); \
    MFMA4(3, 0, (i0) + 3, (j0)); MFMA4(3, 1, (i0) + 3, (j0) + 1); \
    __builtin_amdgcn_s_setprio(0)

// One K-tile = 4 quadrant phases. Stage ledger (verified by simulation):
// PH_A stages A-first(t+1), PH_B stages B-j01(t+1), PH_C stages B-j23(t+1),
// PH_D stages A-second(t+1). vmcnt(4) at A/B/D keeps 4-8 loads in flight;
// each vmcnt retires exactly the half-tile(s) the next phase consumes.
#define TILE(b_, bn_, tn_, DOST, VW_A, VW_B, VW_D) do {                                     \
    const unsigned short* Ab = &As[b_][0];                                                  \
    const unsigned short* Bb = &Bs[b_][0];                                                  \
    /* PH_A: quadrant i0-3 x j0-1 */                                                        \
    RD_A(aA[0][0], 0, 0); RD_A(aA[0][1], 0, 1); RD_A(aA[1][0], 1, 0); RD_A(aA[1][1], 1, 1); \
    RD_A(aA[2][0], 2, 0); RD_A(aA[2][1], 2, 1); RD_A(aA[3][0], 3, 0); RD_A(aA[3][1], 3, 1); \
    RD_B(bB[0][0], 0, 0); RD_B(bB[0][1], 0, 1); RD_B(bB[1][0], 1, 0); RD_B(bB[1][1], 1, 1); \
    if (DOST) { stageA(bn_, 0, tn_); stageA(bn_, 2, tn_); }                                 \
    asm volatile("s_waitcnt lgkmcnt(8)" ::: "memory");                                      \
    VW_A;                                                                                   \
    __builtin_amdgcn_s_barrier();                                                           \
    asm volatile("s_waitcnt lgkmcnt(0)" ::: "memory");                                      \
    CLUSTER(0, 0);                                                                          \
    __builtin_amdgcn_s_barrier();                                                           \
    /* PH_B: i0-3 x j2-3 */                                                                 \
    RD_B(bB[0][0], 2, 0); RD_B(bB[0][1], 2, 1); RD_B(bB[1][0], 3, 0); RD_B(bB[1][1], 3, 1); \
    if (DOST) { stageB(bn_, 0, tn_); stageB(bn_, 1, tn_); }                                 \
    VW_B;                                                                                   \
    __builtin_amdgcn_s_barrier();                                                           \
    asm volatile("s_waitcnt lgkmcnt(0)" ::: "memory");                                      \
    CLUSTER(0, 2);                                                                          \
    __builtin_amdgcn_s_barrier();                                                           \
    /* PH_C: i4-7 x j2-3 (bB still holds j2-3) */                                           \
    RD_A(aA[0][0], 4, 0); RD_A(aA[0][1], 4, 1); RD_A(aA[1][0], 5, 0); RD_A(aA[1][1], 5, 1); \
    RD_A(aA[2][0], 6, 0); RD_A(aA[2][1], 6, 1); RD_A(aA[3][0], 7, 0); RD_A(aA[3][1], 7, 1); \
    if (DOST) { stageB(bn_, 2, tn_); stageB(bn_, 3, tn_); }                                 \
    __builtin_amdgcn_s_barrier();                                                           \
    asm volatile("s_waitcnt lgkmcnt(0)" ::: "memory");                                      \
    CLUSTER(4, 2);                                                                          \
    __builtin_amdgcn_s_barrier();                                                           \
    /* PH_D: i4-7 x j0-1 (re-read B01 from LDS) */                                          \
    RD_B(bB[0][0], 0, 0); RD_B(bB[0][1], 0, 1); RD_B(bB[1][0], 1, 0); RD_B(bB[1][1], 1, 1); \
    if (DOST) { stageA(bn_, 1, tn_); stageA(bn_, 3, tn_); }                                 \
    VW_D;                                                                                   \
    __builtin_amdgcn_s_barrier();                                                           \
    asm volatile("s_waitcnt lgkmcnt(0)" ::: "memory");                                      \
    CLUSTER(4, 0);                                                                          \
    __builtin_amdgcn_s_barrier();                                                           \
} while (0)

    // prologue: tile 0's 4 half-tiles in retirement order
    stageA(0, 0, 0); stageA(0, 2, 0);   // A-first
    stageB(0, 0, 0); stageB(0, 1, 0);   // B-j01
    stageB(0, 2, 0); stageB(0, 3, 0);   // B-j23
    stageA(0, 1, 0); stageA(0, 3, 0);   // A-second
    VMW(4);                              // retire A-first + B-j01
    __builtin_amdgcn_s_barrier();

#pragma unroll 2
    for (int t = 0; t < NT - 1; ++t) {
        int b = t & 1;
        TILE(b, b ^ 1, t + 1, true, VMW(4), VMW(4), VMW(4));
    }
    TILE((NT - 1) & 1, 0, 0, false, VMW(2), VMW(0), NOP0);

#undef RD_A
#undef RD_B
#undef MFMA4
#undef CLUSTER
#undef TILE

    if constexpr (MODE == 1) {
        float bj[4];
#pragma unroll
        for (int j = 0; j < 4; j++) bj[j] = be[col0 + wn * 64 + j * 16 + r16];
#pragma unroll
        for (int i = 0; i < 8; i++) {
#pragma unroll
            for (int rr = 0; rr < 4; rr++) {
                int gs = row0 + wm * 128 + i * 16 + q * 4 + rr;
#pragma unroll
                for (int j = 0; j < 4; j++) {
                    int gn = col0 + wn * 64 + j * 16 + r16;
                    float v = acc[i][j][rr] + bj[j];
                    H[(size_t)gs * DFF + gn] = f2bf(v > 0.f ? v : 0.f);
                }
            }
        }
    } else {
        float* Yp = Y + (size_t)kq * CAP * DMODEL;
#pragma unroll
        for (int i = 0; i < 8; i++) {
#pragma unroll
            for (int rr = 0; rr < 4; rr++) {
                int gs = row0 + wm * 128 + i * 16 + q * 4 + rr;
#pragma unroll
                for (int j = 0; j < 4; j++) {
                    int gn = col0 + wn * 64 + j * 16 + r16;
                    Yp[(size_t)gs * DMODEL + gn] = acc[i][j][rr];
                }
            }
        }
    }
}

// out[t] = g0*(y0[s0]+y1[s0]+b2[e0]) + g1*(y0[s1]+y1[s1]+b2[e1])
__global__ __launch_bounds__(256) void k_combine(const float* __restrict__ Y,
                                                 const int* __restrict__ tg_idx,
                                                 const float* __restrict__ tg_gate,
                                                 const int* __restrict__ sot,
                                                 const float* __restrict__ b2,
                                                 float* __restrict__ out) {
    int t = blockIdx.x;
    int e0 = tg_idx[t * 2], e1 = tg_idx[t * 2 + 1];
    float g0 = tg_gate[t * 2], g1 = tg_gate[t * 2 + 1];
    int s0 = sot[t * 2], s1 = sot[t * 2 + 1];
    const float* y0 = Y;
    const float* y1 = Y + (size_t)CAP * DMODEL;
    int d = threadIdx.x * 4;
    f32x4 a0 = *(const f32x4*)&y0[(size_t)s0 * DMODEL + d];
    f32x4 b0 = *(const f32x4*)&y1[(size_t)s0 * DMODEL + d];
    f32x4 a1 = *(const f32x4*)&y0[(size_t)s1 * DMODEL + d];
    f32x4 b1v = *(const f32x4*)&y1[(size_t)s1 * DMODEL + d];
    f32x4 c0 = *(const f32x4*)&b2[(size_t)e0 * DMODEL + d];
    f32x4 c1 = *(const f32x4*)&b2[(size_t)e1 * DMODEL + d];
    f32x4 r;
#pragma unroll
    for (int i = 0; i < 4; i++)
        r[i] = g0 * (a0[i] + b0[i] + c0[i]) + g1 * (a1[i] + b1v[i] + c1[i]);
    *(f32x4*)&out[(size_t)t * DMODEL + d] = r;
}

extern "C" void kernel_launch(void* const* d_in, const int* in_sizes, int n_in,
                              void* d_out, int out_size, void* d_ws, size_t ws_size,
                              hipStream_t stream) {
    const float* x  = (const float*)d_in[0];
    const float* Wr = (const float*)d_in[1];
    const float* W1 = (const float*)d_in[2];
    const float* b1 = (const float*)d_in[3];
    const float* W2 = (const float*)d_in[4];
    const float* b2 = (const float*)d_in[5];
    float* out = (float*)d_out;

    char* p = (char*)d_ws;
    auto alloc = [&](size_t bytes) {
        char* q = p;
        p += (bytes + 255) & ~(size_t)255;
        return q;
    };
    int*   meta    = (int*)alloc(64 * 4);
    int*   tg_idx  = (int*)alloc((size_t)T_TOK * 2 * 4);
    float* tg_gate = (float*)alloc((size_t)T_TOK * 2 * 4);
    int*   tos     = (int*)alloc((size_t)CAP * 4);
    float* gos     = (float*)alloc((size_t)CAP * 4);
    int*   sot     = (int*)alloc((size_t)T_TOK * 2 * 4);
    unsigned short* xg  = (unsigned short*)alloc((size_t)CAP * DMODEL * 2);
    unsigned short* W1t = (unsigned short*)alloc((size_t)NE * DMODEL * DFF * 2);
    unsigned short* W2t = (unsigned short*)alloc((size_t)NE * DMODEL * DFF * 2);
    unsigned short* h   = (unsigned short*)alloc((size_t)CAP * DFF * 2);
    // y (2 x CAP x DMODEL fp32 = 83.9 MB) aliases xg+W1t (88.1 MB): both dead
    // by the time GEMM2 writes y (GEMM2 reads only h, W2t, meta).
    float* y = (float*)xg;

    hipMemsetAsync(meta, 0, 64 * 4, stream);
    hipMemsetAsync(tos, 0xFF, (size_t)CAP * 4, stream);  // pad slots -> t=-1

    k_router<<<T_TOK / 4, 256, 0, stream>>>(x, Wr, meta, tg_idx, tg_gate);
    k_scan<<<1, 64, 0, stream>>>(meta);
    k_build<<<T_TOK / 256, 256, 0, stream>>>(tg_idx, tg_gate, meta, tos, gos, sot);
    k_gather<<<CAP, 256, 0, stream>>>(x, tos, meta, xg);
    k_transpose2<<<8192, 256, 0, stream>>>(W1, W1t, W2, W2t);
    k_gemm<1><<<dim3(NE * 16 * MT_CAP), 512, 0, stream>>>(xg, W1t, b1, meta, h, nullptr);
    k_gemm<2><<<dim3(NE * 2 * 4 * MT_CAP), 512, 0, stream>>>(h, W2t, b2, meta, nullptr, y);
    k_combine<<<T_TOK, 256, 0, stream>>>(y, tg_idx, tg_gate, sot, b2, out);
}

// Round 6
// 688.094 us; speedup vs baseline: 1.0433x; 1.0433x over previous
//
#include <hip/hip_runtime.h>

// MoE top-2, D=1024, DFF=4096, E=8, T=4096. Sparse grouped-GEMM, bf16 MFMA.
// This round = r0-proven pipeline (atomic router, scan, build, memsets) with
// ONE change under test: k_gemm decodes a linear active-tile id from meta
// (e outer, mt, nt/kq inner -> consecutive blocks share the A panel and walk
// B coherently) instead of the XCD strip pinning, which scattered disjoint
// B-strips across co-resident blocks. GEMM body identical to r0 (128x128,
// BK=64, 4 waves, granule-XOR conflict-free LDS, gld16 staging).

#define T_TOK 4096
#define DMODEL 1024
#define DFF 4096
#define NE 8
#define CAP 9216            // max aligned slots: 8192 + 8*127 -> 9208, padded

typedef __bf16 bf16x8 __attribute__((ext_vector_type(8)));
typedef float f32x4 __attribute__((ext_vector_type(4)));

__device__ __forceinline__ unsigned short f2bf(float f) {
    union { float f; unsigned u; } v; v.f = f;
    unsigned r = v.u + 0x7fffu + ((v.u >> 16) & 1u);
    return (unsigned short)(r >> 16);
}

// async 16B/lane global->LDS. LDS dest = base + lane*16 (wave-uniform base).
__device__ __forceinline__ void gld16(const unsigned short* g, unsigned short* l) {
    __builtin_amdgcn_global_load_lds(
        (const __attribute__((address_space(1))) unsigned int*)g,
        (__attribute__((address_space(3))) unsigned int*)l, 16, 0, 0);
}

// meta layout (ints): [0..7] count, [8..15] cursor, [16..23] aligned, [24..32] off[9], [33] total
__global__ __launch_bounds__(256) void k_router(const float* __restrict__ x,
                                                const float* __restrict__ Wr,
                                                int* __restrict__ meta,
                                                int* __restrict__ tg_idx,
                                                float* __restrict__ tg_gate) {
    int wave = threadIdx.x >> 6, lane = threadIdx.x & 63;
    int t = blockIdx.x * 4 + wave;
    double acc[NE];
#pragma unroll
    for (int e = 0; e < NE; e++) acc[e] = 0.0;
    const float* xr = x + (size_t)t * DMODEL;
#pragma unroll 4
    for (int j = 0; j < 16; j++) {
        int k = j * 64 + lane;
        double xv = (double)xr[k];
        const float4* wr = (const float4*)(Wr + k * NE);
        float4 w0 = wr[0], w1 = wr[1];
        acc[0] += xv * (double)w0.x; acc[1] += xv * (double)w0.y;
        acc[2] += xv * (double)w0.z; acc[3] += xv * (double)w0.w;
        acc[4] += xv * (double)w1.x; acc[5] += xv * (double)w1.y;
        acc[6] += xv * (double)w1.z; acc[7] += xv * (double)w1.w;
    }
#pragma unroll
    for (int off = 32; off; off >>= 1)
#pragma unroll
        for (int e = 0; e < NE; e++) acc[e] += __shfl_xor(acc[e], off);
    if (lane == 0) {
        double v1 = -1e300, v2 = -1e300; int i1 = 0, i2 = 0;
#pragma unroll
        for (int e = 0; e < NE; e++) {
            double v = acc[e];
            if (v > v1) { v2 = v1; i2 = i1; v1 = v; i1 = e; }
            else if (v > v2) { v2 = v; i2 = e; }
        }
        double g1 = 1.0 / (1.0 + exp(v2 - v1));
        tg_idx[t * 2] = i1; tg_idx[t * 2 + 1] = i2;
        tg_gate[t * 2] = (float)g1; tg_gate[t * 2 + 1] = (float)(1.0 - g1);
        atomicAdd(&meta[i1], 1);
        atomicAdd(&meta[i2], 1);
    }
}

__global__ void k_scan(int* __restrict__ meta) {
    if (threadIdx.x == 0) {
        int acc = 0;
        for (int e = 0; e < NE; e++) {
            int a = (meta[e] + 127) & ~127;
            meta[16 + e] = a;
            meta[24 + e] = acc;
            acc += a;
        }
        meta[24 + NE] = acc;
        meta[33] = acc;
    }
}

__global__ __launch_bounds__(256) void k_build(const int* __restrict__ tg_idx,
                                               const float* __restrict__ tg_gate,
                                               int* __restrict__ meta,
                                               int* __restrict__ tos,
                                               float* __restrict__ gos,
                                               int* __restrict__ sot) {
    int t = blockIdx.x * 256 + threadIdx.x;
#pragma unroll
    for (int kk = 0; kk < 2; kk++) {
        int e = tg_idx[t * 2 + kk];
        int pos = atomicAdd(&meta[8 + e], 1);
        int slot = meta[24 + e] + pos;
        tos[slot] = t;
        gos[slot] = tg_gate[t * 2 + kk];
        sot[t * 2 + kk] = slot;
    }
}

__global__ __launch_bounds__(256) void k_gather(const float* __restrict__ x,
                                                const int* __restrict__ tos,
                                                const int* __restrict__ meta,
                                                unsigned short* __restrict__ xg) {
    int s = blockIdx.x;
    if (s >= meta[33]) return;
    int t = tos[s];
    int tid = threadIdx.x;
#pragma unroll
    for (int j = 0; j < 4; j++) {
        int k = tid + j * 256;
        float v = (t >= 0) ? x[(size_t)t * DMODEL + k] : 0.f;
        xg[(size_t)s * DMODEL + k] = f2bf(v);
    }
}

// Both weight transposes in one launch. id<4096: W1 (R=1024,C=4096);
// else W2 (R=4096,C=1024). in [E][R][C] f32 -> out [E][C][R] bf16.
__global__ __launch_bounds__(256) void k_transpose2(const float* __restrict__ W1,
                                                    unsigned short* __restrict__ W1t,
                                                    const float* __restrict__ W2,
                                                    unsigned short* __restrict__ W2t) {
    int id = blockIdx.x;
    const float* in; unsigned short* out; int R, C, rem;
    if (id < 4096) { in = W1; out = W1t; R = DMODEL; C = DFF; rem = id; }
    else           { in = W2; out = W2t; R = DFF; C = DMODEL; rem = id - 4096; }
    int e = rem >> 9, r2 = rem & 511;
    int nbx = C >> 7;
    int bx = r2 % nbx, by = r2 / nbx;
    const float* src = in + (size_t)e * R * C;
    unsigned short* dst = out + (size_t)e * R * C;
    int g = threadIdx.x >> 3, l8 = threadIdx.x & 7;
    int rb = by * 64 + l8 * 8;
    int cb = bx * 128 + g * 4;
    f32x4 v[8];
#pragma unroll
    for (int i = 0; i < 8; i++)
        v[i] = *(const f32x4*)&src[(size_t)(rb + i) * C + cb];
#pragma unroll
    for (int j = 0; j < 4; j++) {
        unsigned short o[8];
#pragma unroll
        for (int i = 0; i < 8; i++) o[i] = f2bf(v[i][j]);
        *(uint4*)&dst[(size_t)(cb + j) * R + rb] = *(uint4*)o;
    }
}

// MODE 1: h = relu(xg @ W1t[e] + b1[e]) -> bf16 H.
// MODE 2: y[kq][slot] = h(kq half) @ W2t[e]  (split-K=2; bias+gate in combine)
// r0 body (128x128, BK=64, 4 waves, 4x4 frags/wave, conflict-free XOR LDS).
// NEW: linear active-tile enumeration from meta (e outer, mt, nt/kq inner).
template <int MODE>
__global__ __launch_bounds__(256, 4) void k_gemm(const unsigned short* __restrict__ A,
                                                 const unsigned short* __restrict__ Bt,
                                                 const float* __restrict__ bias,
                                                 const int* __restrict__ meta,
                                                 unsigned short* __restrict__ H,
                                                 float* __restrict__ Y) {
    constexpr int KFULL = (MODE == 1) ? DMODEL : DFF;
    constexpr int K     = (MODE == 1) ? DMODEL : DFF / 2;  // MODE2: split-K half
    constexpr int N     = (MODE == 1) ? DFF : DMODEL;
    constexpr int TPM   = (MODE == 1) ? (DFF / 128) : (DMODEL / 128) * 2;  // 32 / 16

    int rem = blockIdx.x;
    int e = -1;
#pragma unroll
    for (int ee = 0; ee < NE; ee++) {
        if (e < 0) {
            int te = (meta[16 + ee] >> 7) * TPM;
            if (rem < te) e = ee; else rem -= te;
        }
    }
    if (e < 0) return;
    int mt = rem / TPM;
    int sub = rem - mt * TPM;
    int nt, kq;
    if constexpr (MODE == 1) { nt = sub; kq = 0; }
    else                     { kq = sub >> 3; nt = sub & 7; }
    int row0 = meta[24 + e] + mt * 128;
    int col0 = nt * 128;
    const unsigned short* Ae = A + (size_t)row0 * KFULL + kq * K;
    const unsigned short* Be = Bt + (size_t)e * N * KFULL + (size_t)col0 * KFULL + kq * K;
    const float* be = bias + (size_t)e * N;

    // rows are 64 shorts; chunk c of row r holds global k-chunk c^(r&7)
    // (swizzle on gld16 source; frag reads XOR back -> conflict-free, verified r0/r2).
    __shared__ __align__(16) unsigned short As[128 * 64];
    __shared__ __align__(16) unsigned short Bs[128 * 64];

    int tid = threadIdx.x;
    int lane = tid & 63, wave = tid >> 6;
    int wy = wave >> 1, wx = wave & 1;
    int q = lane >> 4, r16 = lane & 15;

    int srow = lane >> 3;                 // row within 8-row instr group
    int schunk = (lane & 7) ^ srow;       // swizzled global k-chunk for this lane
    int sgoff = srow * KFULL + schunk * 8;

    f32x4 acc[4][4];
#pragma unroll
    for (int i = 0; i < 4; i++)
#pragma unroll
        for (int j = 0; j < 4; j++) acc[i][j] = (f32x4){0.f, 0.f, 0.f, 0.f};

    for (int k0 = 0; k0 < K; k0 += 64) {
        __syncthreads();
#pragma unroll
        for (int it = 0; it < 4; it++) {
            int gr = wave * 32 + it * 8;  // base row of this instr group
            gld16(Ae + (size_t)gr * KFULL + k0 + sgoff, &As[gr * 64]);
            gld16(Be + (size_t)gr * KFULL + k0 + sgoff, &Bs[gr * 64]);
        }
        __syncthreads();
#pragma unroll
        for (int ks = 0; ks < 2; ks++) {
            bf16x8 af[4], bfr[4];
            int sw = (r16 & 7);
#pragma unroll
            for (int i = 0; i < 4; i++) {
                int m = wy * 64 + i * 16 + r16;
                af[i] = *(const bf16x8*)&As[m * 64 + (((ks * 4 + q) ^ sw) << 3)];
            }
#pragma unroll
            for (int j = 0; j < 4; j++) {
                int n = wx * 64 + j * 16 + r16;
                bfr[j] = *(const bf16x8*)&Bs[n * 64 + (((ks * 4 + q) ^ sw) << 3)];
            }
#pragma unroll
            for (int i = 0; i < 4; i++)
#pragma unroll
                for (int j = 0; j < 4; j++)
                    acc[i][j] = __builtin_amdgcn_mfma_f32_16x16x32_bf16(af[i], bfr[j], acc[i][j], 0, 0, 0);
        }
    }

    if constexpr (MODE == 1) {
#pragma unroll
        for (int i = 0; i < 4; i++) {
#pragma unroll
            for (int rr = 0; rr < 4; rr++) {
                int gs = row0 + wy * 64 + i * 16 + q * 4 + rr;
#pragma unroll
                for (int j = 0; j < 4; j++) {
                    int gn = col0 + wx * 64 + j * 16 + r16;
                    float v = acc[i][j][rr] + be[gn];
                    H[(size_t)gs * DFF + gn] = f2bf(v > 0.f ? v : 0.f);
                }
            }
        }
    } else {
        float* Yp = Y + (size_t)kq * CAP * DMODEL;
#pragma unroll
        for (int i = 0; i < 4; i++) {
#pragma unroll
            for (int rr = 0; rr < 4; rr++) {
                int gs = row0 + wy * 64 + i * 16 + q * 4 + rr;
#pragma unroll
                for (int j = 0; j < 4; j++) {
                    int gn = col0 + wx * 64 + j * 16 + r16;
                    Yp[(size_t)gs * DMODEL + gn] = acc[i][j][rr];
                }
            }
        }
    }
}

// out[t] = g0*(y0[s0]+y1[s0]+b2[e0]) + g1*(y0[s1]+y1[s1]+b2[e1])
__global__ __launch_bounds__(256) void k_combine(const float* __restrict__ Y,
                                                 const int* __restrict__ tg_idx,
                                                 const float* __restrict__ tg_gate,
                                                 const int* __restrict__ sot,
                                                 const float* __restrict__ b2,
                                                 float* __restrict__ out) {
    int t = blockIdx.x;
    int e0 = tg_idx[t * 2], e1 = tg_idx[t * 2 + 1];
    float g0 = tg_gate[t * 2], g1 = tg_gate[t * 2 + 1];
    int s0 = sot[t * 2], s1 = sot[t * 2 + 1];
    const float* y0 = Y;
    const float* y1 = Y + (size_t)CAP * DMODEL;
    int d = threadIdx.x * 4;
    f32x4 a0 = *(const f32x4*)&y0[(size_t)s0 * DMODEL + d];
    f32x4 b0 = *(const f32x4*)&y1[(size_t)s0 * DMODEL + d];
    f32x4 a1 = *(const f32x4*)&y0[(size_t)s1 * DMODEL + d];
    f32x4 b1v = *(const f32x4*)&y1[(size_t)s1 * DMODEL + d];
    f32x4 c0 = *(const f32x4*)&b2[(size_t)e0 * DMODEL + d];
    f32x4 c1 = *(const f32x4*)&b2[(size_t)e1 * DMODEL + d];
    f32x4 r;
#pragma unroll
    for (int i = 0; i < 4; i++)
        r[i] = g0 * (a0[i] + b0[i] + c0[i]) + g1 * (a1[i] + b1v[i] + c1[i]);
    *(f32x4*)&out[(size_t)t * DMODEL + d] = r;
}

extern "C" void kernel_launch(void* const* d_in, const int* in_sizes, int n_in,
                              void* d_out, int out_size, void* d_ws, size_t ws_size,
                              hipStream_t stream) {
    const float* x  = (const float*)d_in[0];
    const float* Wr = (const float*)d_in[1];
    const float* W1 = (const float*)d_in[2];
    const float* b1 = (const float*)d_in[3];
    const float* W2 = (const float*)d_in[4];
    const float* b2 = (const float*)d_in[5];
    float* out = (float*)d_out;

    char* p = (char*)d_ws;
    auto alloc = [&](size_t bytes) {
        char* q = p;
        p += (bytes + 255) & ~(size_t)255;
        return q;
    };
    int*   meta    = (int*)alloc(64 * 4);
    int*   tg_idx  = (int*)alloc((size_t)T_TOK * 2 * 4);
    float* tg_gate = (float*)alloc((size_t)T_TOK * 2 * 4);
    int*   tos     = (int*)alloc((size_t)CAP * 4);
    float* gos     = (float*)alloc((size_t)CAP * 4);
    int*   sot     = (int*)alloc((size_t)T_TOK * 2 * 4);
    unsigned short* xg  = (unsigned short*)alloc((size_t)CAP * DMODEL * 2);
    unsigned short* W1t = (unsigned short*)alloc((size_t)NE * DMODEL * DFF * 2);
    unsigned short* W2t = (unsigned short*)alloc((size_t)NE * DMODEL * DFF * 2);
    unsigned short* h   = (unsigned short*)alloc((size_t)CAP * DFF * 2);
    // y (2 x CAP x DMODEL fp32 = 75.5 MB) aliases xg+W1t (83 MB): both are dead
    // by the time GEMM2 writes y (GEMM2 reads only h, W2t, meta).
    float* y = (float*)xg;

    hipMemsetAsync(meta, 0, 64 * 4, stream);
    hipMemsetAsync(tos, 0xFF, (size_t)CAP * 4, stream);  // pad slots -> t=-1

    k_router<<<T_TOK / 4, 256, 0, stream>>>(x, Wr, meta, tg_idx, tg_gate);
    k_scan<<<1, 64, 0, stream>>>(meta);
    k_build<<<T_TOK / 256, 256, 0, stream>>>(tg_idx, tg_gate, meta, tos, gos, sot);
    k_gather<<<CAP, 256, 0, stream>>>(x, tos, meta, xg);
    k_transpose2<<<8192, 256, 0, stream>>>(W1, W1t, W2, W2t);
    k_gemm<1><<<dim3(72 * (DFF / 128)), 256, 0, stream>>>(xg, W1t, b1, meta, h, nullptr);
    k_gemm<2><<<dim3(72 * (DMODEL / 128) * 2), 256, 0, stream>>>(h, W2t, b2, meta, nullptr, y);
    k_combine<<<T_TOK, 256, 0, stream>>>(y, tg_idx, tg_gate, sot, b2, out);
}

// Round 7
// 554.783 us; speedup vs baseline: 1.2941x; 1.2403x over previous
//
#include <hip/hip_runtime.h>

// MoE top-2, D=1024, DFF=4096, E=8, T=4096. Sparse grouped-GEMM, bf16 MFMA.
// r6 GEMM kept verbatim (128x128/BK64, granule-XOR conflict-free LDS, linear
// active-tile enumeration -- measured 117.5us/GEMM, MfmaUtil 24.6, 0 confl).
// NEW this round: atomic-free routing. k_router computes top2+gates only;
// k_pack (8 blocks, one per expert) does exact stable slot packing via a
// packed-u64 histogram (LDS tree reduce, no 64-bit shuffles) + LDS prefix
// scan; writes pad slots and meta. Replaces router-atomics + k_scan +
// k_build + both memsets (16K same-line cross-XCD atomics eliminated).

#define T_TOK 4096
#define DMODEL 1024
#define DFF 4096
#define NE 8
#define CAP 9216            // max aligned slots: 8192 + 8*127 -> 9208, padded

typedef __bf16 bf16x8 __attribute__((ext_vector_type(8)));
typedef float f32x4 __attribute__((ext_vector_type(4)));

__device__ __forceinline__ unsigned short f2bf(float f) {
    union { float f; unsigned u; } v; v.f = f;
    unsigned r = v.u + 0x7fffu + ((v.u >> 16) & 1u);
    return (unsigned short)(r >> 16);
}

// async 16B/lane global->LDS. LDS dest = base + lane*16 (wave-uniform base).
__device__ __forceinline__ void gld16(const unsigned short* g, unsigned short* l) {
    __builtin_amdgcn_global_load_lds(
        (const __attribute__((address_space(1))) unsigned int*)g,
        (__attribute__((address_space(3))) unsigned int*)l, 16, 0, 0);
}

// meta layout (ints): [16..23] aligned count, [24..31] offset, [33] total
__global__ __launch_bounds__(256) void k_router(const float* __restrict__ x,
                                                const float* __restrict__ Wr,
                                                int* __restrict__ tg_idx,
                                                float* __restrict__ tg_gate) {
    int wave = threadIdx.x >> 6, lane = threadIdx.x & 63;
    int t = blockIdx.x * 4 + wave;
    double acc[NE];
#pragma unroll
    for (int e = 0; e < NE; e++) acc[e] = 0.0;
    const float* xr = x + (size_t)t * DMODEL;
#pragma unroll 4
    for (int j = 0; j < 16; j++) {
        int k = j * 64 + lane;
        double xv = (double)xr[k];
        const float4* wr = (const float4*)(Wr + k * NE);
        float4 w0 = wr[0], w1 = wr[1];
        acc[0] += xv * (double)w0.x; acc[1] += xv * (double)w0.y;
        acc[2] += xv * (double)w0.z; acc[3] += xv * (double)w0.w;
        acc[4] += xv * (double)w1.x; acc[5] += xv * (double)w1.y;
        acc[6] += xv * (double)w1.z; acc[7] += xv * (double)w1.w;
    }
#pragma unroll
    for (int off = 32; off; off >>= 1)
#pragma unroll
        for (int e = 0; e < NE; e++) acc[e] += __shfl_xor(acc[e], off);
    if (lane == 0) {
        double v1 = -1e300, v2 = -1e300; int i1 = 0, i2 = 0;
#pragma unroll
        for (int e = 0; e < NE; e++) {
            double v = acc[e];
            if (v > v1) { v2 = v1; i2 = i1; v1 = v; i1 = e; }
            else if (v > v2) { v2 = v; i2 = e; }
        }
        double g1 = 1.0 / (1.0 + exp(v2 - v1));
        tg_idx[t * 2] = i1; tg_idx[t * 2 + 1] = i2;
        tg_gate[t * 2] = (float)g1; tg_gate[t * 2 + 1] = (float)(1.0 - g1);
    }
}

// One block per expert e. Exact, stable, atomic-free packing.
// Histogram: per-thread counts packed in 2 u64 (16-bit fields, experts 0-3 /
// 4-7; per-thread max 32, total max 8192 -> fits), reduced by a plain LDS
// tree (no 64-bit shuffles). Own-expert positions via LDS Hillis-Steele
// exclusive scan. Deterministic: all blocks see identical totals.
__global__ __launch_bounds__(256) void k_pack(const int* __restrict__ tg_idx,
                                              int* __restrict__ meta,
                                              int* __restrict__ tos,
                                              int* __restrict__ sot) {
    const int e = (int)blockIdx.x;
    const int tid = (int)threadIdx.x;
    const int CHUNK = (T_TOK * 2) / 256;     // 32 entries per thread
    __shared__ unsigned long long slo[256];
    __shared__ unsigned long long shi[256];
    __shared__ int tsum[256];

    int base = tid * CHUNK;
    unsigned long long lo = 0, hi = 0;
    int my = 0;
    for (int i = 0; i < CHUNK; i++) {
        int v = tg_idx[base + i];
        unsigned long long inc = 1ull << ((v & 3) * 16);
        if (v < 4) lo += inc; else hi += inc;
        my += (v == e) ? 1 : 0;
    }
    slo[tid] = lo; shi[tid] = hi; tsum[tid] = my;
    __syncthreads();
    for (int off = 128; off > 0; off >>= 1) {
        if (tid < off) {
            slo[tid] += slo[tid + off];
            shi[tid] += shi[tid + off];
        }
        __syncthreads();
    }
    unsigned long long tlo = slo[0], thi = shi[0];
    int cnt[NE];
#pragma unroll
    for (int k = 0; k < 4; k++) {
        cnt[k]     = (int)((tlo >> (k * 16)) & 0xffffu);
        cnt[k + 4] = (int)((thi >> (k * 16)) & 0xffffu);
    }
    int off_e = 0, tot = 0;
#pragma unroll
    for (int k = 0; k < NE; k++) {
        int a = (cnt[k] + 127) & ~127;
        if (k < e) off_e += a;
        tot += a;
    }
    int cnt_e = cnt[e];
    int aligned_e = (cnt_e + 127) & ~127;
    // exclusive prefix over threads of my (tsum untouched since first sync)
    for (int off = 1; off < 256; off <<= 1) {
        int v = (tid >= off) ? tsum[tid - off] : 0;
        __syncthreads();
        tsum[tid] += v;
        __syncthreads();
    }
    int w = off_e + tsum[tid] - my;
    for (int i = 0; i < CHUNK; i++) {
        int idx = base + i;
        if (tg_idx[idx] == e) {
            tos[w] = idx >> 1;
            sot[idx] = w;
            w++;
        }
    }
    for (int i = cnt_e + tid; i < aligned_e; i += 256) tos[off_e + i] = -1;
    if (tid == 0) {
        meta[16 + e] = aligned_e;
        meta[24 + e] = off_e;
        if (e == 0) meta[33] = tot;
    }
}

__global__ __launch_bounds__(256) void k_gather(const float* __restrict__ x,
                                                const int* __restrict__ tos,
                                                const int* __restrict__ meta,
                                                unsigned short* __restrict__ xg) {
    int s = blockIdx.x;
    if (s >= meta[33]) return;
    int t = tos[s];
    int tid = threadIdx.x;
#pragma unroll
    for (int j = 0; j < 4; j++) {
        int k = tid + j * 256;
        float v = (t >= 0) ? x[(size_t)t * DMODEL + k] : 0.f;
        xg[(size_t)s * DMODEL + k] = f2bf(v);
    }
}

// Both weight transposes in one launch. id<4096: W1 (R=1024,C=4096);
// else W2 (R=4096,C=1024). in [E][R][C] f32 -> out [E][C][R] bf16.
__global__ __launch_bounds__(256) void k_transpose2(const float* __restrict__ W1,
                                                    unsigned short* __restrict__ W1t,
                                                    const float* __restrict__ W2,
                                                    unsigned short* __restrict__ W2t) {
    int id = blockIdx.x;
    const float* in; unsigned short* out; int R, C, rem;
    if (id < 4096) { in = W1; out = W1t; R = DMODEL; C = DFF; rem = id; }
    else           { in = W2; out = W2t; R = DFF; C = DMODEL; rem = id - 4096; }
    int e = rem >> 9, r2 = rem & 511;
    int nbx = C >> 7;
    int bx = r2 % nbx, by = r2 / nbx;
    const float* src = in + (size_t)e * R * C;
    unsigned short* dst = out + (size_t)e * R * C;
    int g = threadIdx.x >> 3, l8 = threadIdx.x & 7;
    int rb = by * 64 + l8 * 8;
    int cb = bx * 128 + g * 4;
    f32x4 v[8];
#pragma unroll
    for (int i = 0; i < 8; i++)
        v[i] = *(const f32x4*)&src[(size_t)(rb + i) * C + cb];
#pragma unroll
    for (int j = 0; j < 4; j++) {
        unsigned short o[8];
#pragma unroll
        for (int i = 0; i < 8; i++) o[i] = f2bf(v[i][j]);
        *(uint4*)&dst[(size_t)(cb + j) * R + rb] = *(uint4*)o;
    }
}

// MODE 1: h = relu(xg @ W1t[e] + b1[e]) -> bf16 H.
// MODE 2: y[kq][slot] = h(kq half) @ W2t[e]  (split-K=2; bias+gate in combine)
// r6 body verbatim (128x128, BK=64, 4 waves, 4x4 frags/wave, conflict-free
// XOR LDS, linear active-tile enumeration from meta).
template <int MODE>
__global__ __launch_bounds__(256, 4) void k_gemm(const unsigned short* __restrict__ A,
                                                 const unsigned short* __restrict__ Bt,
                                                 const float* __restrict__ bias,
                                                 const int* __restrict__ meta,
                                                 unsigned short* __restrict__ H,
                                                 float* __restrict__ Y) {
    constexpr int KFULL = (MODE == 1) ? DMODEL : DFF;
    constexpr int K     = (MODE == 1) ? DMODEL : DFF / 2;  // MODE2: split-K half
    constexpr int N     = (MODE == 1) ? DFF : DMODEL;
    constexpr int TPM   = (MODE == 1) ? (DFF / 128) : (DMODEL / 128) * 2;  // 32 / 16

    int rem = blockIdx.x;
    int e = -1;
#pragma unroll
    for (int ee = 0; ee < NE; ee++) {
        if (e < 0) {
            int te = (meta[16 + ee] >> 7) * TPM;
            if (rem < te) e = ee; else rem -= te;
        }
    }
    if (e < 0) return;
    int mt = rem / TPM;
    int sub = rem - mt * TPM;
    int nt, kq;
    if constexpr (MODE == 1) { nt = sub; kq = 0; }
    else                     { kq = sub >> 3; nt = sub & 7; }
    int row0 = meta[24 + e] + mt * 128;
    int col0 = nt * 128;
    const unsigned short* Ae = A + (size_t)row0 * KFULL + kq * K;
    const unsigned short* Be = Bt + (size_t)e * N * KFULL + (size_t)col0 * KFULL + kq * K;
    const float* be = bias + (size_t)e * N;

    // rows are 64 shorts; chunk c of row r holds global k-chunk c^(r&7)
    // (swizzle on gld16 source; frag reads XOR back -> conflict-free).
    __shared__ __align__(16) unsigned short As[128 * 64];
    __shared__ __align__(16) unsigned short Bs[128 * 64];

    int tid = threadIdx.x;
    int lane = tid & 63, wave = tid >> 6;
    int wy = wave >> 1, wx = wave & 1;
    int q = lane >> 4, r16 = lane & 15;

    int srow = lane >> 3;                 // row within 8-row instr group
    int schunk = (lane & 7) ^ srow;       // swizzled global k-chunk for this lane
    int sgoff = srow * KFULL + schunk * 8;

    f32x4 acc[4][4];
#pragma unroll
    for (int i = 0; i < 4; i++)
#pragma unroll
        for (int j = 0; j < 4; j++) acc[i][j] = (f32x4){0.f, 0.f, 0.f, 0.f};

    for (int k0 = 0; k0 < K; k0 += 64) {
        __syncthreads();
#pragma unroll
        for (int it = 0; it < 4; it++) {
            int gr = wave * 32 + it * 8;  // base row of this instr group
            gld16(Ae + (size_t)gr * KFULL + k0 + sgoff, &As[gr * 64]);
            gld16(Be + (size_t)gr * KFULL + k0 + sgoff, &Bs[gr * 64]);
        }
        __syncthreads();
#pragma unroll
        for (int ks = 0; ks < 2; ks++) {
            bf16x8 af[4], bfr[4];
            int sw = (r16 & 7);
#pragma unroll
            for (int i = 0; i < 4; i++) {
                int m = wy * 64 + i * 16 + r16;
                af[i] = *(const bf16x8*)&As[m * 64 + (((ks * 4 + q) ^ sw) << 3)];
            }
#pragma unroll
            for (int j = 0; j < 4; j++) {
                int n = wx * 64 + j * 16 + r16;
                bfr[j] = *(const bf16x8*)&Bs[n * 64 + (((ks * 4 + q) ^ sw) << 3)];
            }
#pragma unroll
            for (int i = 0; i < 4; i++)
#pragma unroll
                for (int j = 0; j < 4; j++)
                    acc[i][j] = __builtin_amdgcn_mfma_f32_16x16x32_bf16(af[i], bfr[j], acc[i][j], 0, 0, 0);
        }
    }

    if constexpr (MODE == 1) {
#pragma unroll
        for (int i = 0; i < 4; i++) {
#pragma unroll
            for (int rr = 0; rr < 4; rr++) {
                int gs = row0 + wy * 64 + i * 16 + q * 4 + rr;
#pragma unroll
                for (int j = 0; j < 4; j++) {
                    int gn = col0 + wx * 64 + j * 16 + r16;
                    float v = acc[i][j][rr] + be[gn];
                    H[(size_t)gs * DFF + gn] = f2bf(v > 0.f ? v : 0.f);
                }
            }
        }
    } else {
        float* Yp = Y + (size_t)kq * CAP * DMODEL;
#pragma unroll
        for (int i = 0; i < 4; i++) {
#pragma unroll
            for (int rr = 0; rr < 4; rr++) {
                int gs = row0 + wy * 64 + i * 16 + q * 4 + rr;
#pragma unroll
                for (int j = 0; j < 4; j++) {
                    int gn = col0 + wx * 64 + j * 16 + r16;
                    Yp[(size_t)gs * DMODEL + gn] = acc[i][j][rr];
                }
            }
        }
    }
}

// out[t] = g0*(y0[s0]+y1[s0]+b2[e0]) + g1*(y0[s1]+y1[s1]+b2[e1])
__global__ __launch_bounds__(256) void k_combine(const float* __restrict__ Y,
                                                 const int* __restrict__ tg_idx,
                                                 const float* __restrict__ tg_gate,
                                                 const int* __restrict__ sot,
                                                 const float* __restrict__ b2,
                                                 float* __restrict__ out) {
    int t = blockIdx.x;
    int e0 = tg_idx[t * 2], e1 = tg_idx[t * 2 + 1];
    float g0 = tg_gate[t * 2], g1 = tg_gate[t * 2 + 1];
    int s0 = sot[t * 2], s1 = sot[t * 2 + 1];
    const float* y0 = Y;
    const float* y1 = Y + (size_t)CAP * DMODEL;
    int d = threadIdx.x * 4;
    f32x4 a0 = *(const f32x4*)&y0[(size_t)s0 * DMODEL + d];
    f32x4 b0 = *(const f32x4*)&y1[(size_t)s0 * DMODEL + d];
    f32x4 a1 = *(const f32x4*)&y0[(size_t)s1 * DMODEL + d];
    f32x4 b1v = *(const f32x4*)&y1[(size_t)s1 * DMODEL + d];
    f32x4 c0 = *(const f32x4*)&b2[(size_t)e0 * DMODEL + d];
    f32x4 c1 = *(const f32x4*)&b2[(size_t)e1 * DMODEL + d];
    f32x4 r;
#pragma unroll
    for (int i = 0; i < 4; i++)
        r[i] = g0 * (a0[i] + b0[i] + c0[i]) + g1 * (a1[i] + b1v[i] + c1[i]);
    *(f32x4*)&out[(size_t)t * DMODEL + d] = r;
}

extern "C" void kernel_launch(void* const* d_in, const int* in_sizes, int n_in,
                              void* d_out, int out_size, void* d_ws, size_t ws_size,
                              hipStream_t stream) {
    const float* x  = (const float*)d_in[0];
    const float* Wr = (const float*)d_in[1];
    const float* W1 = (const float*)d_in[2];
    const float* b1 = (const float*)d_in[3];
    const float* W2 = (const float*)d_in[4];
    const float* b2 = (const float*)d_in[5];
    float* out = (float*)d_out;

    char* p = (char*)d_ws;
    auto alloc = [&](size_t bytes) {
        char* q = p;
        p += (bytes + 255) & ~(size_t)255;
        return q;
    };
    int*   meta    = (int*)alloc(64 * 4);
    int*   tg_idx  = (int*)alloc((size_t)T_TOK * 2 * 4);
    float* tg_gate = (float*)alloc((size_t)T_TOK * 2 * 4);
    int*   tos     = (int*)alloc((size_t)CAP * 4);
    int*   sot     = (int*)alloc((size_t)T_TOK * 2 * 4);
    unsigned short* xg  = (unsigned short*)alloc((size_t)CAP * DMODEL * 2);
    unsigned short* W1t = (unsigned short*)alloc((size_t)NE * DMODEL * DFF * 2);
    unsigned short* W2t = (unsigned short*)alloc((size_t)NE * DMODEL * DFF * 2);
    unsigned short* h   = (unsigned short*)alloc((size_t)CAP * DFF * 2);
    // y (2 x CAP x DMODEL fp32 = 75.5 MB) aliases xg+W1t (83 MB): both are dead
    // by the time GEMM2 writes y (GEMM2 reads only h, W2t, meta).
    float* y = (float*)xg;

    k_router<<<T_TOK / 4, 256, 0, stream>>>(x, Wr, tg_idx, tg_gate);
    k_pack<<<NE, 256, 0, stream>>>(tg_idx, meta, tos, sot);
    k_gather<<<CAP, 256, 0, stream>>>(x, tos, meta, xg);
    k_transpose2<<<8192, 256, 0, stream>>>(W1, W1t, W2, W2t);
    k_gemm<1><<<dim3(72 * (DFF / 128)), 256, 0, stream>>>(xg, W1t, b1, meta, h, nullptr);
    k_gemm<2><<<dim3(72 * (DMODEL / 128) * 2), 256, 0, stream>>>(h, W2t, b2, meta, nullptr, y);
    k_combine<<<T_TOK, 256, 0, stream>>>(y, tg_idx, tg_gate, sot, b2, out);
}